// Round 8
// baseline (1278.632 us; speedup 1.0000x reference)
//
#include <hip/hip_runtime.h>
#include <hip/hip_fp16.h>

#define N_NODES 100000
#define N_EDGES 1250000
#define C 64
#define NPB 128          // nodes per bucket (dst >> 7)
#define NB 782           // ceil(100000/128)
#define CAP 2048         // bucket capacity (mean 1598, sigma 40 -> 11 sigma headroom)
#define P1_CHUNKQ 2048   // int4-quads per partition block = 8192 edges
#define P1_BLOCKS 153    // ceil(312500 / 2048)

typedef int vint4 __attribute__((ext_vector_type(4)));

// ---------------- pass 1: partition edges into dst-buckets ----------------
// LDS histogram per 8K-edge chunk -> one global atomic per (block,bucket)
// reservation -> scattered-but-run-grouped packed writes ((src<<7)|dst_local).
__global__ __launch_bounds__(256) void partition_kernel(
        const int* __restrict__ src, const int* __restrict__ dst,
        int* __restrict__ gcnt, unsigned int* __restrict__ packed) {
    __shared__ int hist[NB];
    __shared__ int gbase[NB];
    const int t = threadIdx.x;
    for (int i = t; i < NB; i += 256) hist[i] = 0;
    __syncthreads();

    const int qbase = blockIdx.x * P1_CHUNKQ;
    const int NQ = N_EDGES / 4;  // 312500
    const vint4* d4 = (const vint4*)dst;
    const vint4* s4 = (const vint4*)src;

    // phase A: LDS histogram of this chunk
    for (int i = 0; i < P1_CHUNKQ; i += 256) {
        int q = qbase + i + t;
        if (q < NQ) {
            vint4 d = __builtin_nontemporal_load(&d4[q]);
            atomicAdd(&hist[d.x >> 7], 1);
            atomicAdd(&hist[d.y >> 7], 1);
            atomicAdd(&hist[d.z >> 7], 1);
            atomicAdd(&hist[d.w >> 7], 1);
        }
    }
    __syncthreads();

    // phase B: reserve contiguous runs in each bucket; reuse hist as cursor
    for (int b = t; b < NB; b += 256) {
        int h = hist[b];
        gbase[b] = (h > 0) ? (b * CAP + atomicAdd(&gcnt[b], h)) : 0;
        hist[b] = 0;
    }
    __syncthreads();

    // phase C: scatter packed edges into reserved runs
    for (int i = 0; i < P1_CHUNKQ; i += 256) {
        int q = qbase + i + t;
        if (q < NQ) {
            vint4 d = __builtin_nontemporal_load(&d4[q]);
            vint4 s = __builtin_nontemporal_load(&s4[q]);
            int bb, lp, pos;
            bb = d.x >> 7; lp = atomicAdd(&hist[bb], 1); pos = gbase[bb] + lp;
            if (pos < (bb + 1) * CAP) packed[pos] = ((unsigned)s.x << 7) | (unsigned)(d.x & 127);
            bb = d.y >> 7; lp = atomicAdd(&hist[bb], 1); pos = gbase[bb] + lp;
            if (pos < (bb + 1) * CAP) packed[pos] = ((unsigned)s.y << 7) | (unsigned)(d.y & 127);
            bb = d.z >> 7; lp = atomicAdd(&hist[bb], 1); pos = gbase[bb] + lp;
            if (pos < (bb + 1) * CAP) packed[pos] = ((unsigned)s.z << 7) | (unsigned)(d.z & 127);
            bb = d.w >> 7; lp = atomicAdd(&hist[bb], 1); pos = gbase[bb] + lp;
            if (pos < (bb + 1) * CAP) packed[pos] = ((unsigned)s.w << 7) | (unsigned)(d.w & 127);
        }
    }
}

// ---------------- dense: z = x @ W_l (fp16), r = x @ W_r + b (fp32) ----------------
__global__ __launch_bounds__(256) void dense_kernel(
        const float* x,
        const float* __restrict__ wl, const float* __restrict__ wr,
        const float* __restrict__ bl,
        __half* __restrict__ z, float* r, int n_nodes) {
    __shared__ float s_w[C][2 * C];
    __shared__ float s_x[64][C + 1];

    const int t = threadIdx.x;
    const int base = blockIdx.x * 64;

    for (int i = t; i < C * C; i += 256) {
        int k = i >> 6, c = i & 63;
        s_w[k][c] = wl[i];
        s_w[k][64 + c] = wr[i];
    }
    for (int i = t; i < 1024; i += 256) {
        int n = i >> 4;
        int kq = i & 15;
        float4 v = make_float4(0.f, 0.f, 0.f, 0.f);
        if (base + n < n_nodes) v = ((const float4*)x)[((size_t)(base + n) << 4) + kq];
        s_x[n][kq * 4 + 0] = v.x;
        s_x[n][kq * 4 + 1] = v.y;
        s_x[n][kq * 4 + 2] = v.z;
        s_x[n][kq * 4 + 3] = v.w;
    }
    __syncthreads();

    const int lane = t & 63;
    const int wv = t >> 6;
    const int cg = lane & 15;
    const int q = lane >> 4;
    const int n0 = wv * 16 + 4 * q;

    float4 bv = ((const float4*)bl)[cg];
    float accz[4][4];
    float accr[4][4];
#pragma unroll
    for (int i = 0; i < 4; ++i) {
        accz[i][0] = accz[i][1] = accz[i][2] = accz[i][3] = 0.f;
        accr[i][0] = bv.x; accr[i][1] = bv.y; accr[i][2] = bv.z; accr[i][3] = bv.w;
    }

#pragma unroll 8
    for (int k = 0; k < C; ++k) {
        float4 wlv = *(const float4*)&s_w[k][4 * cg];
        float4 wrv = *(const float4*)&s_w[k][64 + 4 * cg];
        float xk[4];
#pragma unroll
        for (int i = 0; i < 4; ++i) xk[i] = s_x[n0 + i][k];
#pragma unroll
        for (int i = 0; i < 4; ++i) {
            accz[i][0] += xk[i] * wlv.x;
            accz[i][1] += xk[i] * wlv.y;
            accz[i][2] += xk[i] * wlv.z;
            accz[i][3] += xk[i] * wlv.w;
            accr[i][0] += xk[i] * wrv.x;
            accr[i][1] += xk[i] * wrv.y;
            accr[i][2] += xk[i] * wrv.z;
            accr[i][3] += xk[i] * wrv.w;
        }
    }

#pragma unroll
    for (int i = 0; i < 4; ++i) {
        size_t gn = (size_t)base + n0 + i;
        if (gn < (size_t)n_nodes) {
            __half2 p0 = __float22half2_rn(make_float2(accz[i][0], accz[i][1]));
            __half2 p1 = __float22half2_rn(make_float2(accz[i][2], accz[i][3]));
            ((__half2*)z)[gn * 32 + 2 * cg + 0] = p0;
            ((__half2*)z)[gn * 32 + 2 * cg + 1] = p1;
            ((float4*)r)[gn * 16 + cg] = make_float4(accr[i][0], accr[i][1], accr[i][2], accr[i][3]);
        }
    }
}

// ---------------- fused gather-aggregate + mean + residual + PReLU ----------------
// Block = one 128-node bucket. fp32 accumulator tile in LDS (bank = ch%32 ->
// 2-way alias, free). Half-wave per edge, lane = __half2 channel pair, 8 row
// gathers in flight. Epilogue: mean + r + PReLU, coalesced write. out may
// alias r (block owns its node range exclusively; read-before-write per node).
__global__ __launch_bounds__(256) void fused_agg_kernel(
        const __half* __restrict__ z,
        const float* r,
        const unsigned int* __restrict__ packed,
        const int* __restrict__ gcnt,
        const float* __restrict__ a,
        float* out) {
    __shared__ float accum[NPB][C];   // 32 KB
    __shared__ float scnt[NPB];

    const int t = threadIdx.x;
    const int b = blockIdx.x;
    const int w = t >> 6;
    const int lane = t & 63;
    const int h = lane >> 5;   // half-wave id
    const int m = lane & 31;   // channel pair (ch 2m, 2m+1)

    for (int i = t; i < NPB * C; i += 256) ((float*)accum)[i] = 0.f;
    if (t < NPB) scnt[t] = 0.f;
    __syncthreads();

    const int nb = min(gcnt[b], CAP);
    const unsigned int* bp = packed + (size_t)b * CAP;
    const __half2* zz = (const __half2*)z;

    for (int base = w * 64; base < nb; base += 256) {
        unsigned int uvec = 0;
        if (base + lane < nb) uvec = __builtin_nontemporal_load(&bp[base + lane]);
        int lim = min(nb - base, 64);
        for (int s = 0; s < lim; s += 16) {   // 8 edges per half-wave per unroll
            float2 vals[8];
            int dls[8];
            bool act[8];
#pragma unroll
            for (int i = 0; i < 8; ++i) {
                int ej = s + 2 * i + h;
                unsigned int u = __shfl(uvec, ej);
                act[i] = ej < lim;
                int srcn = act[i] ? (int)(u >> 7) : 0;
                dls[i] = (int)(u & 127u);
                vals[i] = __half22float2(zz[(size_t)srcn * 32 + m]);
            }
#pragma unroll
            for (int i = 0; i < 8; ++i) {
                if (act[i]) {
                    atomicAdd(&accum[dls[i]][2 * m + 0], vals[i].x);
                    atomicAdd(&accum[dls[i]][2 * m + 1], vals[i].y);
                    if (m == 0) atomicAdd(&scnt[dls[i]], 1.0f);
                }
            }
        }
    }
    __syncthreads();

    // epilogue: wave per node, lane = channel
    float av = a[lane];
    for (int nn = w; nn < NPB; nn += 4) {
        int gn = b * NPB + nn;
        if (gn < N_NODES) {
            float sum = accum[nn][lane];
            float c = scnt[nn];
            float rv = r[(size_t)gn * C + lane];
            float hh = sum / fmaxf(c, 1.0f) + rv;
            out[(size_t)gn * C + lane] = hh >= 0.0f ? hh : av * hh;
        }
    }
}

extern "C" void kernel_launch(void* const* d_in, const int* in_sizes, int n_in,
                              void* d_out, int out_size, void* d_ws, size_t ws_size,
                              hipStream_t stream) {
    const float* x    = (const float*)d_in[0];
    const int*   ei   = (const int*)d_in[1];
    const float* w_l0 = (const float*)d_in[2];
    const float* b_l0 = (const float*)d_in[3];
    const float* w_r0 = (const float*)d_in[4];
    const float* a0   = (const float*)d_in[5];
    const float* w_l1 = (const float*)d_in[6];
    const float* b_l1 = (const float*)d_in[7];
    const float* w_r1 = (const float*)d_in[8];
    const float* a1   = (const float*)d_in[9];
    float* out = (float*)d_out;

    const int* src = ei;            // edge_index[0, :]
    const int* dst = ei + N_EDGES;  // edge_index[1, :]

    // ws: gcnt[1024] | packed[NB*CAP] | Z(fp16 N*C) | B(fp32 N*C)
    int* gcnt            = (int*)d_ws;
    unsigned int* packed = (unsigned int*)(gcnt + 1024);
    __half* Z            = (__half*)(packed + (size_t)NB * CAP);
    float* B             = (float*)(Z + (size_t)N_NODES * C);

    hipMemsetAsync(gcnt, 0, 1024 * sizeof(int), stream);

    const int dblocks = (N_NODES + 63) / 64;

    partition_kernel<<<P1_BLOCKS, 256, 0, stream>>>(src, dst, gcnt, packed);

    // Layer 0: z=Z, r=B; fused writes h1 into B (in-place safe per block)
    dense_kernel<<<dblocks, 256, 0, stream>>>(x, w_l0, w_r0, b_l0, Z, B, N_NODES);
    fused_agg_kernel<<<NB, 256, 0, stream>>>(Z, B, packed, gcnt, a0, B);

    // Layer 1: x=B (in-place dense), fused -> d_out
    dense_kernel<<<dblocks, 256, 0, stream>>>(B, w_l1, w_r1, b_l1, Z, B, N_NODES);
    fused_agg_kernel<<<NB, 256, 0, stream>>>(Z, B, packed, gcnt, a1, out);
}

// Round 9
// 279.554 us; speedup vs baseline: 4.5738x; 4.5738x over previous
//
#include <hip/hip_runtime.h>
#include <hip/hip_fp16.h>

#define N_NODES 100000
#define N_EDGES 1250000
#define C 64
#define NPB 128          // nodes per bucket (dst >> 7)
#define NB 782           // ceil(100000/128)
#define CAP 2048         // bucket capacity (mean 1598, sigma 40 -> 11 sigma headroom)
#define P1_CHUNKQ 2048   // int4-quads per partition block = 8192 edges
#define P1_BLOCKS 153    // ceil(312500 / 2048)

typedef int vint4 __attribute__((ext_vector_type(4)));

// ---------------- pass 1: partition edges into 128-node dst-buckets ----------------
// LDS histogram per 8K-edge chunk -> one global atomic per (block,bucket)
// reservation -> run-grouped packed writes ((src<<7)|dst_local).
__global__ __launch_bounds__(256) void partition_kernel(
        const int* __restrict__ src, const int* __restrict__ dst,
        int* __restrict__ gcnt, unsigned int* __restrict__ packed) {
    __shared__ int hist[NB];
    __shared__ int gbase[NB];
    const int t = threadIdx.x;
    for (int i = t; i < NB; i += 256) hist[i] = 0;
    __syncthreads();

    const int qbase = blockIdx.x * P1_CHUNKQ;
    const int NQ = N_EDGES / 4;  // 312500
    const vint4* d4 = (const vint4*)dst;
    const vint4* s4 = (const vint4*)src;

    for (int i = 0; i < P1_CHUNKQ; i += 256) {
        int q = qbase + i + t;
        if (q < NQ) {
            vint4 d = __builtin_nontemporal_load(&d4[q]);
            atomicAdd(&hist[d.x >> 7], 1);
            atomicAdd(&hist[d.y >> 7], 1);
            atomicAdd(&hist[d.z >> 7], 1);
            atomicAdd(&hist[d.w >> 7], 1);
        }
    }
    __syncthreads();

    for (int b = t; b < NB; b += 256) {
        int h = hist[b];
        gbase[b] = (h > 0) ? (b * CAP + atomicAdd(&gcnt[b], h)) : 0;
        hist[b] = 0;
    }
    __syncthreads();

    for (int i = 0; i < P1_CHUNKQ; i += 256) {
        int q = qbase + i + t;
        if (q < NQ) {
            vint4 d = __builtin_nontemporal_load(&d4[q]);
            vint4 s = __builtin_nontemporal_load(&s4[q]);
            int bb, lp, pos;
            bb = d.x >> 7; lp = atomicAdd(&hist[bb], 1); pos = gbase[bb] + lp;
            if (pos < (bb + 1) * CAP) packed[pos] = ((unsigned)s.x << 7) | (unsigned)(d.x & 127);
            bb = d.y >> 7; lp = atomicAdd(&hist[bb], 1); pos = gbase[bb] + lp;
            if (pos < (bb + 1) * CAP) packed[pos] = ((unsigned)s.y << 7) | (unsigned)(d.y & 127);
            bb = d.z >> 7; lp = atomicAdd(&hist[bb], 1); pos = gbase[bb] + lp;
            if (pos < (bb + 1) * CAP) packed[pos] = ((unsigned)s.z << 7) | (unsigned)(d.z & 127);
            bb = d.w >> 7; lp = atomicAdd(&hist[bb], 1); pos = gbase[bb] + lp;
            if (pos < (bb + 1) * CAP) packed[pos] = ((unsigned)s.w << 7) | (unsigned)(d.w & 127);
        }
    }
}

// ---------------- pass 2: exclusive scan of bucket counts ----------------
__global__ __launch_bounds__(1024) void scan_gcnt_kernel(const int* __restrict__ gcnt,
                                                         int* __restrict__ bbase,
                                                         int* __restrict__ offsets) {
    __shared__ int s[1024];
    int t = threadIdx.x;
    int v = (t < NB) ? gcnt[t] : 0;
    s[t] = v;
    __syncthreads();
    for (int off = 1; off < 1024; off <<= 1) {
        int u = (t >= off) ? s[t - off] : 0;
        __syncthreads();
        s[t] += u;
        __syncthreads();
    }
    if (t < NB) bbase[t] = s[t] - v;  // exclusive
    if (t == 0) offsets[N_NODES] = N_EDGES;
}

// ---------------- pass 3: per-bucket LDS counting sort -> CSR ----------------
// Block = bucket. Reads contiguous; writes land in one ~6.4 KB burst -> lines
// fill before eviction (kills the old 10x scatter write amplification).
__global__ __launch_bounds__(256) void sort_kernel(
        const unsigned int* __restrict__ packed,
        const int* __restrict__ gcnt, const int* __restrict__ bbase,
        int* __restrict__ offsets, int* __restrict__ sorted_src) {
    __shared__ unsigned int s_e[CAP];  // 8 KB
    __shared__ int s_hist[NPB];
    __shared__ int s_excl[NPB];
    const int b = blockIdx.x;
    const int t = threadIdx.x;
    const int nb = min(gcnt[b], CAP);
    const int base = bbase[b];

    for (int i = t; i < NPB; i += 256) s_hist[i] = 0;
    __syncthreads();
    for (int i = t; i < nb; i += 256) {
        unsigned int u = packed[(size_t)b * CAP + i];
        s_e[i] = u;
        atomicAdd(&s_hist[u & 127u], 1);
    }
    __syncthreads();
    if (t < NPB) s_excl[t] = s_hist[t];
    __syncthreads();
    for (int off = 1; off < NPB; off <<= 1) {
        int v = (t < NPB && t >= off) ? s_excl[t - off] : 0;
        __syncthreads();
        if (t < NPB) s_excl[t] += v;
        __syncthreads();
    }
    if (t < NPB) {
        int excl = s_excl[t] - s_hist[t];
        s_hist[t] = excl;  // becomes cursor
        int node = b * NPB + t;
        if (node < N_NODES) offsets[node] = base + excl;
    }
    __syncthreads();
    for (int i = t; i < nb; i += 256) {
        unsigned int u = s_e[i];
        int lp = atomicAdd(&s_hist[u & 127u], 1);
        sorted_src[base + lp] = (int)(u >> 7);
    }
}

// ---------------- dense: z = x @ W_l (fp16), r = x @ W_r + b (fp32) ----------------
__global__ __launch_bounds__(256) void dense_kernel(
        const float* x,
        const float* __restrict__ wl, const float* __restrict__ wr,
        const float* __restrict__ bl,
        __half* __restrict__ z, float* r, int n_nodes) {
    __shared__ float s_w[C][2 * C];
    __shared__ float s_x[64][C + 1];

    const int t = threadIdx.x;
    const int base = blockIdx.x * 64;

    for (int i = t; i < C * C; i += 256) {
        int k = i >> 6, c = i & 63;
        s_w[k][c] = wl[i];
        s_w[k][64 + c] = wr[i];
    }
    for (int i = t; i < 1024; i += 256) {
        int n = i >> 4;
        int kq = i & 15;
        float4 v = make_float4(0.f, 0.f, 0.f, 0.f);
        if (base + n < n_nodes) v = ((const float4*)x)[((size_t)(base + n) << 4) + kq];
        s_x[n][kq * 4 + 0] = v.x;
        s_x[n][kq * 4 + 1] = v.y;
        s_x[n][kq * 4 + 2] = v.z;
        s_x[n][kq * 4 + 3] = v.w;
    }
    __syncthreads();

    const int lane = t & 63;
    const int wv = t >> 6;
    const int cg = lane & 15;
    const int q = lane >> 4;
    const int n0 = wv * 16 + 4 * q;

    float4 bv = ((const float4*)bl)[cg];
    float accz[4][4];
    float accr[4][4];
#pragma unroll
    for (int i = 0; i < 4; ++i) {
        accz[i][0] = accz[i][1] = accz[i][2] = accz[i][3] = 0.f;
        accr[i][0] = bv.x; accr[i][1] = bv.y; accr[i][2] = bv.z; accr[i][3] = bv.w;
    }

#pragma unroll 8
    for (int k = 0; k < C; ++k) {
        float4 wlv = *(const float4*)&s_w[k][4 * cg];
        float4 wrv = *(const float4*)&s_w[k][64 + 4 * cg];
        float xk[4];
#pragma unroll
        for (int i = 0; i < 4; ++i) xk[i] = s_x[n0 + i][k];
#pragma unroll
        for (int i = 0; i < 4; ++i) {
            accz[i][0] += xk[i] * wlv.x;
            accz[i][1] += xk[i] * wlv.y;
            accz[i][2] += xk[i] * wlv.z;
            accz[i][3] += xk[i] * wlv.w;
            accr[i][0] += xk[i] * wrv.x;
            accr[i][1] += xk[i] * wrv.y;
            accr[i][2] += xk[i] * wrv.z;
            accr[i][3] += xk[i] * wrv.w;
        }
    }

#pragma unroll
    for (int i = 0; i < 4; ++i) {
        size_t gn = (size_t)base + n0 + i;
        if (gn < (size_t)n_nodes) {
            __half2 p0 = __float22half2_rn(make_float2(accz[i][0], accz[i][1]));
            __half2 p1 = __float22half2_rn(make_float2(accz[i][2], accz[i][3]));
            ((__half2*)z)[gn * 32 + 2 * cg + 0] = p0;
            ((__half2*)z)[gn * 32 + 2 * cg + 1] = p1;
            ((float4*)r)[gn * 16 + cg] = make_float4(accr[i][0], accr[i][1], accr[i][2], accr[i][3]);
        }
    }
}

// ---------------- gather: h = PReLU( mean_j z[nbr_j] + r ) ----------------
// Proven R5 shape: wave per node, lane = channel, 8 fp16 rows in flight.
__global__ __launch_bounds__(256) void gather_kernel(
        const __half* __restrict__ z,
        const float* r,
        const int* __restrict__ offsets,
        const int* __restrict__ sorted_src,
        const float* __restrict__ a,
        float* out) {
    const int lane = threadIdx.x & 63;
    const int node = (blockIdx.x << 2) + (threadIdx.x >> 6);

    const int beg = offsets[node];
    const int deg = offsets[node + 1] - beg;

    float acc = 0.0f;
    for (int j = 0; j < deg; j += 8) {
        int last = deg - 1;
        int s0 = sorted_src[beg + min(j + 0, last)];
        int s1 = sorted_src[beg + min(j + 1, last)];
        int s2 = sorted_src[beg + min(j + 2, last)];
        int s3 = sorted_src[beg + min(j + 3, last)];
        int s4 = sorted_src[beg + min(j + 4, last)];
        int s5 = sorted_src[beg + min(j + 5, last)];
        int s6 = sorted_src[beg + min(j + 6, last)];
        int s7 = sorted_src[beg + min(j + 7, last)];
        float v0 = __half2float(z[(size_t)s0 * C + lane]);
        float v1 = __half2float(z[(size_t)s1 * C + lane]);
        float v2 = __half2float(z[(size_t)s2 * C + lane]);
        float v3 = __half2float(z[(size_t)s3 * C + lane]);
        float v4 = __half2float(z[(size_t)s4 * C + lane]);
        float v5 = __half2float(z[(size_t)s5 * C + lane]);
        float v6 = __half2float(z[(size_t)s6 * C + lane]);
        float v7 = __half2float(z[(size_t)s7 * C + lane]);
        float sum = v0;
        sum += (j + 1 < deg) ? v1 : 0.0f;
        sum += (j + 2 < deg) ? v2 : 0.0f;
        sum += (j + 3 < deg) ? v3 : 0.0f;
        sum += (j + 4 < deg) ? v4 : 0.0f;
        sum += (j + 5 < deg) ? v5 : 0.0f;
        sum += (j + 6 < deg) ? v6 : 0.0f;
        sum += (j + 7 < deg) ? v7 : 0.0f;
        acc += sum;
    }
    float rv = r[(size_t)node * C + lane];
    float h = acc / (float)max(deg, 1) + rv;
    float av = a[lane];
    out[(size_t)node * C + lane] = h >= 0.0f ? h : av * h;
}

extern "C" void kernel_launch(void* const* d_in, const int* in_sizes, int n_in,
                              void* d_out, int out_size, void* d_ws, size_t ws_size,
                              hipStream_t stream) {
    const float* x    = (const float*)d_in[0];
    const int*   ei   = (const int*)d_in[1];
    const float* w_l0 = (const float*)d_in[2];
    const float* b_l0 = (const float*)d_in[3];
    const float* w_r0 = (const float*)d_in[4];
    const float* a0   = (const float*)d_in[5];
    const float* w_l1 = (const float*)d_in[6];
    const float* b_l1 = (const float*)d_in[7];
    const float* w_r1 = (const float*)d_in[8];
    const float* a1   = (const float*)d_in[9];
    float* out = (float*)d_out;

    const int* src = ei;            // edge_index[0, :]
    const int* dst = ei + N_EDGES;  // edge_index[1, :]

    // ws: gcnt[1024] | bbase[1024] | offsets[N+1] | packed[NB*CAP] | sorted_src[E] | Z(fp16) | B(fp32)
    int* gcnt            = (int*)d_ws;
    int* bbase           = gcnt + 1024;
    int* offsets         = bbase + 1024;
    unsigned int* packed = (unsigned int*)(offsets + (N_NODES + 1));
    int* sorted_src      = (int*)(packed + (size_t)NB * CAP);
    __half* Z            = (__half*)(sorted_src + N_EDGES);
    float* B             = (float*)(Z + (size_t)N_NODES * C);

    hipMemsetAsync(gcnt, 0, 1024 * sizeof(int), stream);

    const int dblocks = (N_NODES + 63) / 64;
    const int nblocks = N_NODES / 4;  // exact

    partition_kernel<<<P1_BLOCKS, 256, 0, stream>>>(src, dst, gcnt, packed);
    scan_gcnt_kernel<<<1, 1024, 0, stream>>>(gcnt, bbase, offsets);
    sort_kernel<<<NB, 256, 0, stream>>>(packed, gcnt, bbase, offsets, sorted_src);

    // Layer 0: z=Z, r=B; gather writes h1 into B (row-aligned alias with r)
    dense_kernel<<<dblocks, 256, 0, stream>>>(x, w_l0, w_r0, b_l0, Z, B, N_NODES);
    gather_kernel<<<nblocks, 256, 0, stream>>>(Z, B, offsets, sorted_src, a0, B);

    // Layer 1: x=B, z=Z, r=B (in-place per-block safe); gather -> d_out
    dense_kernel<<<dblocks, 256, 0, stream>>>(B, w_l1, w_r1, b_l1, Z, B, N_NODES);
    gather_kernel<<<nblocks, 256, 0, stream>>>(Z, B, offsets, sorted_src, a1, out);
}